// Round 8
// baseline (583.429 us; speedup 1.0000x reference)
//
#include <hip/hip_runtime.h>

typedef unsigned short UB;
typedef __attribute__((ext_vector_type(8))) __bf16 bf16x8;
typedef __attribute__((ext_vector_type(4))) __bf16 bf16x4;
typedef __attribute__((ext_vector_type(4))) float floatx4;
typedef __attribute__((ext_vector_type(4))) short short4v;

// ---------- helpers ----------
__device__ __forceinline__ UB f2bf(float f) {
    unsigned int x = __float_as_uint(f);
    unsigned int r = (x + 0x7fffu + ((x >> 16) & 1u)) >> 16;
    return (UB)r;
}

// fast gelu: tanh via exp2 + rcp (~11 VALU ops, err ~1e-6)
__device__ __forceinline__ float gelu_f(float v) {
    const float K = 2.3022083f;            // 2*sqrt(2/pi)*log2(e)
    const float v2 = v * v;
    const float u = v * fmaf(0.044715f, v2, 1.0f);
    float arg = K * u;
    arg = fminf(fmaxf(arg, -80.f), 80.f);  // v_med3
    const float e = __builtin_amdgcn_exp2f(arg);
    const float th = (e - 1.0f) * __builtin_amdgcn_rcpf(e + 1.0f);
    const float hv = 0.5f * v;
    return fmaf(hv, th, hv);
}

// ---------- fp32 [K][N] -> bf16 [N][K] transpose ----------
__global__ __launch_bounds__(256)
void transpose_w_kernel(const float* __restrict__ W, UB* __restrict__ Wt, int K, int N)
{
    __shared__ float tile[32][33];
    const int n0 = blockIdx.x * 32;
    const int k0 = blockIdx.y * 32;
    const int x = threadIdx.x & 31;
    const int y = threadIdx.x >> 5;  // 0..7
#pragma unroll
    for (int j = 0; j < 32; j += 8)
        tile[y + j][x] = W[(size_t)(k0 + y + j) * N + n0 + x];
    __syncthreads();
#pragma unroll
    for (int j = 0; j < 32; j += 8)
        Wt[(size_t)(n0 + y + j) * K + k0 + x] = f2bf(tile[x][y + j]);
}

// ---------- LayerNorm fp32 -> bf16, one block per row, E=1024 ----------
__global__ __launch_bounds__(256)
void layernorm_kernel(const float* __restrict__ x, const float* __restrict__ g,
                      const float* __restrict__ bta, UB* __restrict__ out)
{
    __shared__ float red[8];
    const int row = blockIdx.x;
    const float* xr = x + (size_t)row * 1024;
    float v[4];
    float sum = 0.f, sumsq = 0.f;
#pragma unroll
    for (int i = 0; i < 4; ++i) {
        v[i] = xr[threadIdx.x + i * 256];
        sum += v[i];
        sumsq += v[i] * v[i];
    }
#pragma unroll
    for (int off = 32; off > 0; off >>= 1) {
        sum += __shfl_down(sum, off);
        sumsq += __shfl_down(sumsq, off);
    }
    const int w = threadIdx.x >> 6;
    if ((threadIdx.x & 63) == 0) { red[w * 2] = sum; red[w * 2 + 1] = sumsq; }
    __syncthreads();
    if (threadIdx.x == 0) {
        float s = 0.f, s2 = 0.f;
#pragma unroll
        for (int i = 0; i < 4; ++i) { s += red[i * 2]; s2 += red[i * 2 + 1]; }
        red[0] = s * (1.0f / 1024.0f);
        red[1] = s2 * (1.0f / 1024.0f);
    }
    __syncthreads();
    const float mu = red[0];
    const float var = red[1] - mu * mu;
    const float rs = rsqrtf(var + 1e-5f);
#pragma unroll
    for (int i = 0; i < 4; ++i) {
        const int e = threadIdx.x + i * 256;
        out[(size_t)row * 1024 + e] = f2bf((v[i] - mu) * rs * g[e] + bta[e]);
    }
}

// ---------- reduce: tgt += partial + res + bias  (fp32, N=1024) ----------
__global__ __launch_bounds__(256)
void reduce_kernel(float* __restrict__ tgt, const float* __restrict__ p_lo,
                   const float* __restrict__ p_hi, int rowSplit,
                   const float* __restrict__ res, const float* __restrict__ bias)
{
    const int i = blockIdx.x * 256 + threadIdx.x;  // float4 index
    const int row = i >> 8;
    const int col4 = i & 255;
    const float* p = (row < rowSplit) ? (p_lo + (size_t)row * 1024)
                                      : (p_hi + (size_t)(row - rowSplit) * 1024);
    const float4 t = ((const float4*)&tgt[(size_t)row * 1024])[col4];
    const float4 q = ((const float4*)p)[col4];
    const float4 r = ((const float4*)&res[(size_t)row * 1024])[col4];
    const float4 b = ((const float4*)bias)[col4];
    float4 o = make_float4(t.x + q.x + r.x + b.x, t.y + q.y + r.y + b.y,
                           t.z + q.z + r.z + b.z, t.w + q.w + r.w + b.w);
    ((float4*)&tgt[(size_t)row * 1024])[col4] = o;
}

// ---------- fused: x1 = x1 + partial + res + bias (store fp32), then LN -> bf16 ----------
__global__ __launch_bounds__(256)
void reduce_ln_kernel(float* __restrict__ tgt, const float* __restrict__ p_lo,
                      const float* __restrict__ p_hi, int rowSplit,
                      const float* __restrict__ res, const float* __restrict__ bias,
                      const float* __restrict__ g, const float* __restrict__ bta,
                      UB* __restrict__ outb)
{
    __shared__ float red[8];
    const int row = blockIdx.x;
    const int col4 = threadIdx.x;                  // float4 column
    const float* p = (row < rowSplit) ? (p_lo + (size_t)row * 1024)
                                      : (p_hi + (size_t)(row - rowSplit) * 1024);
    const float4 t = ((const float4*)&tgt[(size_t)row * 1024])[col4];
    const float4 q = ((const float4*)p)[col4];
    const float4 r = ((const float4*)&res[(size_t)row * 1024])[col4];
    const float4 b = ((const float4*)bias)[col4];
    float s[4];
    s[0] = t.x + q.x + r.x + b.x; s[1] = t.y + q.y + r.y + b.y;
    s[2] = t.z + q.z + r.z + b.z; s[3] = t.w + q.w + r.w + b.w;
    ((float4*)&tgt[(size_t)row * 1024])[col4] = make_float4(s[0], s[1], s[2], s[3]);

    float sum = s[0] + s[1] + s[2] + s[3];
    float sumsq = s[0]*s[0] + s[1]*s[1] + s[2]*s[2] + s[3]*s[3];
#pragma unroll
    for (int off = 32; off > 0; off >>= 1) {
        sum += __shfl_down(sum, off);
        sumsq += __shfl_down(sumsq, off);
    }
    const int w = threadIdx.x >> 6;
    if ((threadIdx.x & 63) == 0) { red[w * 2] = sum; red[w * 2 + 1] = sumsq; }
    __syncthreads();
    if (threadIdx.x == 0) {
        float a = 0.f, a2 = 0.f;
#pragma unroll
        for (int i = 0; i < 4; ++i) { a += red[i * 2]; a2 += red[i * 2 + 1]; }
        red[0] = a * (1.0f / 1024.0f);
        red[1] = a2 * (1.0f / 1024.0f);
    }
    __syncthreads();
    const float mu = red[0];
    const float var = red[1] - mu * mu;
    const float rs = rsqrtf(var + 1e-5f);
    const float4 gg = ((const float4*)g)[col4];
    const float4 bb = ((const float4*)bta)[col4];
    UB o4[4];
    o4[0] = f2bf((s[0] - mu) * rs * gg.x + bb.x);
    o4[1] = f2bf((s[1] - mu) * rs * gg.y + bb.y);
    o4[2] = f2bf((s[2] - mu) * rs * gg.z + bb.z);
    o4[3] = f2bf((s[3] - mu) * rs * gg.w + bb.w);
    *(ushort4*)&outb[(size_t)row * 1024 + col4 * 4] = *(ushort4*)o4;
}

// ---------- GEMM v3: barrier-free, LDS-free direct-register K-loop ----------
// 128x128 block tile, 4 waves, wave-tile 64x64. Both operands K-major bf16.
// Fragments loaded straight to VGPRs (b128, quad shares a 64B line; 2nd wave
// L1-hits). MFMA computes C^T (operands swapped) so each lane owns 4
// consecutive-n values -> packed ushort4/float4 stores.
// MODE 0: out bf16 +bias   MODE 2: out bf16 gelu(+bias)
// MODE 4: split-K partial, fp32 (z0 -> outp; z>0 -> pz_lo/pz_hi by rowSplit)
template<int MODE>
__global__ __launch_bounds__(256, 3)
void gemm_direct_kernel(const UB* __restrict__ A, const UB* __restrict__ Bt,
                        const float* __restrict__ bias,
                        void* __restrict__ outp, float* __restrict__ pz_lo,
                        float* __restrict__ pz_hi, int rowSplit,
                        int M, int N, int K, int kLen)
{
    const int tid = threadIdx.x;
    const int lane = tid & 63;
    const int w = tid >> 6;
    const int l15 = lane & 15;
    const int lq = lane >> 4;
    const int lq8 = lq * 8;
    const int wm = (w >> 1) * 64;
    const int wn = (w & 1) * 64;
    const int m0 = blockIdx.y * 128;
    const int n0 = blockIdx.x * 128;
    const int kBase = blockIdx.z * kLen;

    const UB* aP[4];
    const UB* bP[4];
#pragma unroll
    for (int i = 0; i < 4; ++i) {
        aP[i] = A + (size_t)(m0 + wm + i * 16 + l15) * K + kBase + lq8;
        bP[i] = Bt + (size_t)(n0 + wn + i * 16 + l15) * K + kBase + lq8;
    }

    floatx4 acc[4][4];
#pragma unroll
    for (int i = 0; i < 4; ++i)
#pragma unroll
        for (int j = 0; j < 4; ++j)
            acc[i][j] = (floatx4){0.f, 0.f, 0.f, 0.f};

    bf16x8 a0[4], b0[4], a1[4], b1[4];
#pragma unroll
    for (int i = 0; i < 4; ++i) {
        a0[i] = *(const bf16x8*)(aP[i]);
        b0[i] = *(const bf16x8*)(bP[i]);
    }

    for (int ks = 0; ks < kLen; ks += 64) {
        // prefetch second half-tile (ks+32)
#pragma unroll
        for (int i = 0; i < 4; ++i) {
            a1[i] = *(const bf16x8*)(aP[i] + ks + 32);
            b1[i] = *(const bf16x8*)(bP[i] + ks + 32);
        }
        // compute on first half (C^T: operands swapped)
#pragma unroll
        for (int mi = 0; mi < 4; ++mi)
#pragma unroll
            for (int ni = 0; ni < 4; ++ni)
                acc[mi][ni] = __builtin_amdgcn_mfma_f32_16x16x32_bf16(b0[ni], a0[mi], acc[mi][ni], 0, 0, 0);
        // prefetch next tile's first half (ks+64)
        if (ks + 64 < kLen) {
#pragma unroll
            for (int i = 0; i < 4; ++i) {
                a0[i] = *(const bf16x8*)(aP[i] + ks + 64);
                b0[i] = *(const bf16x8*)(bP[i] + ks + 64);
            }
        }
        // compute on second half
#pragma unroll
        for (int mi = 0; mi < 4; ++mi)
#pragma unroll
            for (int ni = 0; ni < 4; ++ni)
                acc[mi][ni] = __builtin_amdgcn_mfma_f32_16x16x32_bf16(b1[ni], a1[mi], acc[mi][ni], 0, 0, 0);
    }

    // epilogue: lane (l15, lq) of tile (mi,ni) holds m = wm+mi*16+l15,
    // n = wn+ni*16+lq*4+{0..3} -> packed stores along n
    const int mBase = m0 + wm + l15;
    const int nBase = n0 + wn + lq * 4;
    if (MODE == 4) {
        float* base;
        int roff;
        if (blockIdx.z == 0) { base = (float*)outp; roff = 0; }
        else if (m0 < rowSplit) { base = pz_lo; roff = 0; }
        else { base = pz_hi; roff = rowSplit; }
#pragma unroll
        for (int mi = 0; mi < 4; ++mi) {
            const int row = mBase + mi * 16 - roff;
#pragma unroll
            for (int ni = 0; ni < 4; ++ni) {
                float4 st = make_float4(acc[mi][ni][0], acc[mi][ni][1],
                                        acc[mi][ni][2], acc[mi][ni][3]);
                *(float4*)&base[(size_t)row * N + nBase + ni * 16] = st;
            }
        }
    } else {
#pragma unroll
        for (int mi = 0; mi < 4; ++mi) {
            const int row = mBase + mi * 16;
#pragma unroll
            for (int ni = 0; ni < 4; ++ni) {
                const int ncol = nBase + ni * 16;
                const float4 b4 = *(const float4*)&bias[ncol];
                float v0 = acc[mi][ni][0] + b4.x;
                float v1 = acc[mi][ni][1] + b4.y;
                float v2 = acc[mi][ni][2] + b4.z;
                float v3 = acc[mi][ni][3] + b4.w;
                if (MODE == 2) { v0 = gelu_f(v0); v1 = gelu_f(v1); v2 = gelu_f(v2); v3 = gelu_f(v3); }
                UB o4[4];
                o4[0] = f2bf(v0); o4[1] = f2bf(v1); o4[2] = f2bf(v2); o4[3] = f2bf(v3);
                *(ushort4*)&((UB*)outp)[(size_t)row * N + ncol] = *(ushort4*)o4;
            }
        }
    }
}

// ---------- Flash attention v4 (causal): S^T trick, register-only P ----------
__global__ __launch_bounds__(256)
void flash_attn_kernel(const UB* __restrict__ qkv, UB* __restrict__ outb)
{
    __shared__ UB Ks[64][72];               // 9216 B
    __shared__ unsigned int VtsP[64][36];   // 9216 B, V^T pair-packed, XOR-swizzled

    const int tid = threadIdx.x;
    const int lane = tid & 63;
    const int w = tid >> 6;
    const int l15 = lane & 15;
    const int lq = lane >> 4;
    const int lq8 = lq * 8;

    const int bh = blockIdx.x;              // b*16+h
    const int b = bh >> 4;
    const int h = bh & 15;
    const int by = blockIdx.y;              // 0..31
    const int qt = (by < 16) ? (2 * by + 1) : (62 - 2 * by);   // pairs sum to 31

    const UB* qbase = qkv + (size_t)(b * 2048) * 3072 + h * 64;
    const UB* kbase = qbase + 1024;
    const UB* vbase = qbase + 2048;

    const int q0w = qt * 64 + w * 16;       // wave's first Q row
    const int qrow = q0w + l15;             // lane's q row

    bf16x8 qf[2];
#pragma unroll
    for (int kk = 0; kk < 2; ++kk)
        qf[kk] = *(const bf16x8*)&qbase[(size_t)qrow * 3072 + kk * 32 + lq8];

    floatx4 o[4];                           // O^T: row d = nd*16+lq*4+r, col q = l15
#pragma unroll
    for (int nd = 0; nd < 4; ++nd) o[nd] = (floatx4){0.f, 0.f, 0.f, 0.f};
    float m_r = -1e30f, l_r = 0.f;

    const int krow = tid >> 3;
    const int kch8 = (tid & 7) * 8;
    const int vq = tid >> 3;
    const int vd0 = (tid & 7) * 8;
    const unsigned int vcol = ((((unsigned)vq >> 2) ^ (((unsigned)vd0 >> 3) & 7)) << 2) | (vq & 3);

    const UB* kp0 = kbase + (size_t)krow * 3072 + kch8;
    const UB* kp1 = kp0 + (size_t)32 * 3072;
    const UB* vp0 = vbase + (size_t)(2 * vq) * 3072 + vd0;
    const UB* vp1 = vp0 + 3072;

    uint4 ka = *(const uint4*)kp0;
    uint4 kb = *(const uint4*)kp1;
    uint4 va = *(const uint4*)vp0;
    uint4 vb = *(const uint4*)vp1;

    const float SCL = 0.18033688011112042f;   // 0.125 * log2(e)

    for (int kt = 0; kt <= qt; ++kt) {
        __syncthreads();
        *(uint4*)&Ks[krow][kch8] = ka;
        *(uint4*)&Ks[krow + 32][kch8] = kb;
        {
            const UB* va16 = (const UB*)&va;
            const UB* vb16 = (const UB*)&vb;
#pragma unroll
            for (int j = 0; j < 8; ++j)
                VtsP[vd0 + j][vcol] = (unsigned int)va16[j] | ((unsigned int)vb16[j] << 16);
        }
        __syncthreads();
        if (kt < qt) {
            const size_t off = (size_t)(kt + 1) * 64 * 3072;
            ka = *(const uint4*)(kp0 + off);
            kb = *(const uint4*)(kp1 + off);
            va = *(const uint4*)(vp0 + off);
            vb = *(const uint4*)(vp1 + off);
        }

        const bool needmask = (kt == qt);
        floatx4 sacc[4];                    // S^T: row k = nj*16+lq*4+r, col q = l15
#pragma unroll
        for (int nj = 0; nj < 4; ++nj) {
            bf16x8 ak0 = *(const bf16x8*)&Ks[nj * 16 + l15][lq8];
            bf16x8 ak1 = *(const bf16x8*)&Ks[nj * 16 + l15][32 + lq8];
            floatx4 acc = (floatx4){0.f, 0.f, 0.f, 0.f};
            acc = __builtin_amdgcn_mfma_f32_16x16x32_bf16(ak0, qf[0], acc, 0, 0, 0);
            acc = __builtin_amdgcn_mfma_f32_16x16x32_bf16(ak1, qf[1], acc, 0, 0, 0);
            sacc[nj] = acc;
        }
#pragma unroll
        for (int nj = 0; nj < 4; ++nj)
#pragma unroll
            for (int r = 0; r < 4; ++r) {
                float v = sacc[nj][r] * SCL;
                if (needmask) {
                    const int kcol = kt * 64 + nj * 16 + lq * 4 + r;
                    v = (kcol > qrow) ? -1e30f : v;
                }
                sacc[nj][r] = v;
            }
        {
            float mx = sacc[0][0];
#pragma unroll
            for (int nj = 0; nj < 4; ++nj)
#pragma unroll
                for (int r = 0; r < 4; ++r) mx = fmaxf(mx, sacc[nj][r]);
            mx = fmaxf(mx, __shfl_xor(mx, 16));
            mx = fmaxf(mx, __shfl_xor(mx, 32));
            const float mnew = fmaxf(m_r, mx);
            const float al = __builtin_amdgcn_exp2f(m_r - mnew);
            m_r = mnew;
            float sl = 0.f;
#pragma unroll
            for (int nj = 0; nj < 4; ++nj)
#pragma unroll
                for (int r = 0; r < 4; ++r) {
                    const float p = __builtin_amdgcn_exp2f(sacc[nj][r] - mnew);
                    sacc[nj][r] = p;
                    sl += p;
                }
            sl += __shfl_xor(sl, 16);
            sl += __shfl_xor(sl, 32);
            l_r = l_r * al + sl;
#pragma unroll
            for (int nd = 0; nd < 4; ++nd)
#pragma unroll
                for (int r = 0; r < 4; ++r) o[nd][r] *= al;
        }
#pragma unroll
        for (int nj = 0; nj < 4; ++nj) {
            union { unsigned int u[2]; short4v s; } bp;   // P^T B-frag: k=lq*4+j, n=l15
            bp.u[0] = __builtin_amdgcn_perm(__float_as_uint(sacc[nj][1]),
                                            __float_as_uint(sacc[nj][0]), 0x07060302u);
            bp.u[1] = __builtin_amdgcn_perm(__float_as_uint(sacc[nj][3]),
                                            __float_as_uint(sacc[nj][2]), 0x07060302u);
#pragma unroll
            for (int nd = 0; nd < 4; ++nd) {
                const int d = nd * 16 + l15;
                const int vqb = nj * 2 + (lq >> 1);
                const int col = ((vqb ^ ((d >> 3) & 7)) << 2) | ((lq & 1) * 2);
                short4v aa = *(const short4v*)&VtsP[d][col];   // V^T[d][nj*16+lq*4+j]
                o[nd] = __builtin_amdgcn_mfma_f32_16x16x16bf16_1k(aa, bp.s, o[nd], 0, 0, 0);
            }
        }
    }

    {
        const float inv = 1.0f / l_r;
        UB* orow = outb + (size_t)(b * 2048 + qrow) * 1024 + h * 64;
#pragma unroll
        for (int nd = 0; nd < 4; ++nd) {
            UB o4[4];
#pragma unroll
            for (int r = 0; r < 4; ++r) o4[r] = f2bf(o[nd][r] * inv);
            *(ushort4*)&orow[nd * 16 + lq * 4] = *(ushort4*)o4;
        }
    }
}

// ---------- launch ----------
extern "C" void kernel_launch(void* const* d_in, const int* in_sizes, int n_in,
                              void* d_out, int out_size, void* d_ws, size_t ws_size,
                              hipStream_t stream) {
    const float* x        = (const float*)d_in[0];
    const float* c_attn_w = (const float*)d_in[1];
    const float* c_attn_b = (const float*)d_in[2];
    const float* c_proj_w = (const float*)d_in[3];
    const float* c_proj_b = (const float*)d_in[4];
    const float* mlp_w1   = (const float*)d_in[5];
    const float* mlp_b1   = (const float*)d_in[6];
    const float* mlp_w2   = (const float*)d_in[7];
    const float* mlp_b2   = (const float*)d_in[8];
    const float* ln1_g    = (const float*)d_in[9];
    const float* ln1_b    = (const float*)d_in[10];
    const float* ln2_g    = (const float*)d_in[11];
    const float* ln2_b    = (const float*)d_in[12];
    float* out = (float*)d_out;

    // workspace layout (bytes)
    char* ws = (char*)d_ws;
    UB*    ln_buf  = (UB*)(ws);                          //  8,388,608
    UB*    big_buf = (UB*)(ws + 8388608);                // 33,554,432 (qkv / proj-partial / h1)
    UB*    attout  = (UB*)(ws + 41943040);               //  8,388,608 (attn out / mlp2-partial-lo)
    float* x1      = (float*)(ws + 50331648);            // 16,777,216
    UB*    wt_attn = (UB*)(ws + 67108864);               //  6,291,456
    UB*    wt_proj = (UB*)(ws + 73400320);               //  2,097,152
    UB*    wt_mlp1 = (UB*)(ws + 75497472);               //  8,388,608
    UB*    wt_mlp2 = (UB*)(ws + 83886080);               //  8,388,608

    // 1. transpose weights fp32[K][N] -> bf16[N][K]
    transpose_w_kernel<<<dim3(96, 32), 256, 0, stream>>>(c_attn_w, wt_attn, 1024, 3072);
    transpose_w_kernel<<<dim3(32, 32), 256, 0, stream>>>(c_proj_w, wt_proj, 1024, 1024);
    transpose_w_kernel<<<dim3(128, 32), 256, 0, stream>>>(mlp_w1, wt_mlp1, 1024, 4096);
    transpose_w_kernel<<<dim3(32, 128), 256, 0, stream>>>(mlp_w2, wt_mlp2, 4096, 1024);

    // 2. LN1
    layernorm_kernel<<<4096, 256, 0, stream>>>(x, ln1_g, ln1_b, ln_buf);

    // 3. QKV = LN1 @ Wqkv + b : [4096][3072] bf16 (768 blocks, 3/CU)
    gemm_direct_kernel<0><<<dim3(24, 32, 1), 256, 0, stream>>>(ln_buf, wt_attn, c_attn_b,
                                                               big_buf, nullptr, nullptr, 0,
                                                               4096, 3072, 1024, 1024);

    // 4. attention (64-row Q tiles, 1024 blocks)
    flash_attn_kernel<<<dim3(32, 32), 256, 0, stream>>>(big_buf, attout);

    // 5. proj split-K=2 (512 blocks): z0 -> x1, z1 -> big_buf
    gemm_direct_kernel<4><<<dim3(8, 32, 2), 256, 0, stream>>>(attout, wt_proj, nullptr,
                                                              x1, (float*)big_buf, (float*)big_buf, 4096,
                                                              4096, 1024, 1024, 512);
    //    fused: x1 += partial + x + b_proj ; ln_buf = LN2(x1)
    reduce_ln_kernel<<<4096, 256, 0, stream>>>(x1, (float*)big_buf, (float*)big_buf, 4096,
                                               x, c_proj_b, ln2_g, ln2_b, ln_buf);

    // 7. h1 = gelu(LN2 @ W1 + b1) : bf16 [4096][4096] (1024 blocks)
    gemm_direct_kernel<2><<<dim3(32, 32, 1), 256, 0, stream>>>(ln_buf, wt_mlp1, mlp_b1,
                                                               big_buf, nullptr, nullptr, 0,
                                                               4096, 4096, 1024, 1024);

    // 8. MLP2 split-K=2 (512 blocks): z0 -> out, z1 -> attout/ln_buf
    gemm_direct_kernel<4><<<dim3(8, 32, 2), 256, 0, stream>>>(big_buf, wt_mlp2, nullptr,
                                                              out, (float*)attout, (float*)ln_buf, 2048,
                                                              4096, 1024, 4096, 2048);
    //    out += partial + x1 + b2
    reduce_kernel<<<4096, 256, 0, stream>>>(out, (float*)attout, (float*)ln_buf, 2048,
                                            x1, mlp_b2);
}

// Round 9
// 331.018 us; speedup vs baseline: 1.7625x; 1.7625x over previous
//
#include <hip/hip_runtime.h>

typedef unsigned short UB;
typedef __attribute__((ext_vector_type(8))) __bf16 bf16x8;
typedef __attribute__((ext_vector_type(4))) __bf16 bf16x4;
typedef __attribute__((ext_vector_type(4))) float floatx4;
typedef __attribute__((ext_vector_type(4))) short short4v;

#define GAS __attribute__((address_space(1)))
#define LAS __attribute__((address_space(3)))

// ---------- helpers ----------
__device__ __forceinline__ UB f2bf(float f) {
    unsigned int x = __float_as_uint(f);
    unsigned int r = (x + 0x7fffu + ((x >> 16) & 1u)) >> 16;
    return (UB)r;
}

// fast gelu: tanh via exp2 + rcp (~11 VALU ops, err ~1e-6)
__device__ __forceinline__ float gelu_f(float v) {
    const float K = 2.3022083f;            // 2*sqrt(2/pi)*log2(e)
    const float v2 = v * v;
    const float u = v * fmaf(0.044715f, v2, 1.0f);
    float arg = K * u;
    arg = fminf(fmaxf(arg, -80.f), 80.f);  // v_med3
    const float e = __builtin_amdgcn_exp2f(arg);
    const float th = (e - 1.0f) * __builtin_amdgcn_rcpf(e + 1.0f);
    const float hv = 0.5f * v;
    return fmaf(hv, th, hv);
}

// async 16B global -> LDS (lds dest: wave-uniform base + lane*16)
__device__ __forceinline__ void gload16(const UB* g, UB* l) {
    __builtin_amdgcn_global_load_lds((const GAS unsigned int*)g,
                                     (LAS unsigned int*)l, 16, 0, 0);
}

// ---------- fp32 [K][N] -> bf16 [N][K] transpose ----------
__global__ __launch_bounds__(256)
void transpose_w_kernel(const float* __restrict__ W, UB* __restrict__ Wt, int K, int N)
{
    __shared__ float tile[32][33];
    const int n0 = blockIdx.x * 32;
    const int k0 = blockIdx.y * 32;
    const int x = threadIdx.x & 31;
    const int y = threadIdx.x >> 5;  // 0..7
#pragma unroll
    for (int j = 0; j < 32; j += 8)
        tile[y + j][x] = W[(size_t)(k0 + y + j) * N + n0 + x];
    __syncthreads();
#pragma unroll
    for (int j = 0; j < 32; j += 8)
        Wt[(size_t)(n0 + y + j) * K + k0 + x] = f2bf(tile[x][y + j]);
}

// ---------- LayerNorm fp32 -> bf16, one block per row, E=1024 ----------
__global__ __launch_bounds__(256)
void layernorm_kernel(const float* __restrict__ x, const float* __restrict__ g,
                      const float* __restrict__ bta, UB* __restrict__ out)
{
    __shared__ float red[8];
    const int row = blockIdx.x;
    const float* xr = x + (size_t)row * 1024;
    float v[4];
    float sum = 0.f, sumsq = 0.f;
#pragma unroll
    for (int i = 0; i < 4; ++i) {
        v[i] = xr[threadIdx.x + i * 256];
        sum += v[i];
        sumsq += v[i] * v[i];
    }
#pragma unroll
    for (int off = 32; off > 0; off >>= 1) {
        sum += __shfl_down(sum, off);
        sumsq += __shfl_down(sumsq, off);
    }
    const int w = threadIdx.x >> 6;
    if ((threadIdx.x & 63) == 0) { red[w * 2] = sum; red[w * 2 + 1] = sumsq; }
    __syncthreads();
    if (threadIdx.x == 0) {
        float s = 0.f, s2 = 0.f;
#pragma unroll
        for (int i = 0; i < 4; ++i) { s += red[i * 2]; s2 += red[i * 2 + 1]; }
        red[0] = s * (1.0f / 1024.0f);
        red[1] = s2 * (1.0f / 1024.0f);
    }
    __syncthreads();
    const float mu = red[0];
    const float var = red[1] - mu * mu;
    const float rs = rsqrtf(var + 1e-5f);
#pragma unroll
    for (int i = 0; i < 4; ++i) {
        const int e = threadIdx.x + i * 256;
        out[(size_t)row * 1024 + e] = f2bf((v[i] - mu) * rs * g[e] + bta[e]);
    }
}

// ---------- reduce: tgt += partial + res + bias  (fp32, N=1024) ----------
__global__ __launch_bounds__(256)
void reduce_kernel(float* __restrict__ tgt, const float* __restrict__ p_lo,
                   const float* __restrict__ p_hi, int rowSplit,
                   const float* __restrict__ res, const float* __restrict__ bias)
{
    const int i = blockIdx.x * 256 + threadIdx.x;  // float4 index
    const int row = i >> 8;
    const int col4 = i & 255;
    const float* p = (row < rowSplit) ? (p_lo + (size_t)row * 1024)
                                      : (p_hi + (size_t)(row - rowSplit) * 1024);
    const float4 t = ((const float4*)&tgt[(size_t)row * 1024])[col4];
    const float4 q = ((const float4*)p)[col4];
    const float4 r = ((const float4*)&res[(size_t)row * 1024])[col4];
    const float4 b = ((const float4*)bias)[col4];
    float4 o = make_float4(t.x + q.x + r.x + b.x, t.y + q.y + r.y + b.y,
                           t.z + q.z + r.z + b.z, t.w + q.w + r.w + b.w);
    ((float4*)&tgt[(size_t)row * 1024])[col4] = o;
}

// ---------- fused: x1 = x1 + partial + res + bias (store fp32), then LN -> bf16 ----------
__global__ __launch_bounds__(256)
void reduce_ln_kernel(float* __restrict__ tgt, const float* __restrict__ p_lo,
                      const float* __restrict__ p_hi, int rowSplit,
                      const float* __restrict__ res, const float* __restrict__ bias,
                      const float* __restrict__ g, const float* __restrict__ bta,
                      UB* __restrict__ outb)
{
    __shared__ float red[8];
    const int row = blockIdx.x;
    const int col4 = threadIdx.x;                  // float4 column
    const float* p = (row < rowSplit) ? (p_lo + (size_t)row * 1024)
                                      : (p_hi + (size_t)(row - rowSplit) * 1024);
    const float4 t = ((const float4*)&tgt[(size_t)row * 1024])[col4];
    const float4 q = ((const float4*)p)[col4];
    const float4 r = ((const float4*)&res[(size_t)row * 1024])[col4];
    const float4 b = ((const float4*)bias)[col4];
    float s[4];
    s[0] = t.x + q.x + r.x + b.x; s[1] = t.y + q.y + r.y + b.y;
    s[2] = t.z + q.z + r.z + b.z; s[3] = t.w + q.w + r.w + b.w;
    ((float4*)&tgt[(size_t)row * 1024])[col4] = make_float4(s[0], s[1], s[2], s[3]);

    float sum = s[0] + s[1] + s[2] + s[3];
    float sumsq = s[0]*s[0] + s[1]*s[1] + s[2]*s[2] + s[3]*s[3];
#pragma unroll
    for (int off = 32; off > 0; off >>= 1) {
        sum += __shfl_down(sum, off);
        sumsq += __shfl_down(sumsq, off);
    }
    const int w = threadIdx.x >> 6;
    if ((threadIdx.x & 63) == 0) { red[w * 2] = sum; red[w * 2 + 1] = sumsq; }
    __syncthreads();
    if (threadIdx.x == 0) {
        float a = 0.f, a2 = 0.f;
#pragma unroll
        for (int i = 0; i < 4; ++i) { a += red[i * 2]; a2 += red[i * 2 + 1]; }
        red[0] = a * (1.0f / 1024.0f);
        red[1] = a2 * (1.0f / 1024.0f);
    }
    __syncthreads();
    const float mu = red[0];
    const float var = red[1] - mu * mu;
    const float rs = rsqrtf(var + 1e-5f);
    const float4 gg = ((const float4*)g)[col4];
    const float4 bb = ((const float4*)bta)[col4];
    UB o4[4];
    o4[0] = f2bf((s[0] - mu) * rs * gg.x + bb.x);
    o4[1] = f2bf((s[1] - mu) * rs * gg.y + bb.y);
    o4[2] = f2bf((s[2] - mu) * rs * gg.z + bb.z);
    o4[3] = f2bf((s[3] - mu) * rs * gg.w + bb.w);
    *(ushort4*)&outb[(size_t)row * 1024 + col4 * 4] = *(ushort4*)o4;
}

// ---------- GEMM v4: LDS-staged, BK=64, XOR-8 swizzle (conflict-free b128 reads)
// BM=128 x BN x 64; 4 waves; wave tile 64 x (BN/2).
// LDS chunk layout: row = 64 elems (8 x 16B slots); lane fetches GLOBAL slot
// (c&7)^(row&7) into LDS slot (c&7) -> fragment read at slot (kk*4+lq)^(l15&7)
// spreads all 32 banks (8 words/bank = size floor). DMA global: per-8-lane
// permutation within two 64B lines (still coalesced).
// MODE 0: bf16 +bias   MODE 2: bf16 gelu(+bias)   MODE 4: split-K fp32 partial
template<int MODE, int BN>
__global__ __launch_bounds__(256, (BN == 128) ? 3 : 2)
void gemm_bt_kernel(const UB* __restrict__ A, const UB* __restrict__ Bt,
                    const float* __restrict__ bias,
                    void* __restrict__ outp, float* __restrict__ pz_lo,
                    float* __restrict__ pz_hi, int rowSplit,
                    int M, int N, int K, int kLen)
{
    constexpr int NI = BN / 32;        // n-frags per wave per kk (4 or 8)
    constexpr int NB = BN / 32;        // B DMA instrs per thread (4 or 8)
    __shared__ UB As[128 * 64];        // 16 KB
    __shared__ UB Bs[BN * 64];         // 16/32 KB
    const int tid = threadIdx.x;
    const int lane = tid & 63;
    const int w = tid >> 6;
    const int l15 = lane & 15;
    const int lq = lane >> 4;
    const int wm = (w >> 1) * 64;
    const int wn = (w & 1) * (BN / 2);
    const int m0 = blockIdx.y * 128;
    const int n0 = blockIdx.x * BN;
    const int kBase = blockIdx.z * kLen;
    const int e7 = l15 & 7;            // row&7 for all fragment rows

    // DMA pointers: A 4 instrs (1024 chunks), B NB instrs
    const UB* aG[4];
    UB* aL[4];
#pragma unroll
    for (int j = 0; j < 4; ++j) {
        const int c = j * 256 + w * 64 + lane;
        const int row = c >> 3;
        const int g = (c & 7) ^ (row & 7);
        aG[j] = A + (size_t)(m0 + row) * K + kBase + g * 8;
        aL[j] = As + (size_t)(j * 256 + w * 64) * 8;
    }
    const UB* bG[NB];
    UB* bL[NB];
#pragma unroll
    for (int j = 0; j < NB; ++j) {
        const int c = j * 256 + w * 64 + lane;
        const int row = c >> 3;
        const int g = (c & 7) ^ (row & 7);
        bG[j] = Bt + (size_t)(n0 + row) * K + kBase + g * 8;
        bL[j] = Bs + (size_t)(j * 256 + w * 64) * 8;
    }

    floatx4 acc[4][NI];
#pragma unroll
    for (int i = 0; i < 4; ++i)
#pragma unroll
        for (int j = 0; j < NI; ++j)
            acc[i][j] = (floatx4){0.f, 0.f, 0.f, 0.f};

    for (int ks = 0; ks < kLen; ks += 64) {
        __syncthreads();
#pragma unroll
        for (int j = 0; j < 4; ++j) gload16(aG[j] + ks, aL[j]);
#pragma unroll
        for (int j = 0; j < NB; ++j) gload16(bG[j] + ks, bL[j]);
        __syncthreads();

#pragma unroll
        for (int kk = 0; kk < 2; ++kk) {
            bf16x8 af[4], bfr[NI];
#pragma unroll
            for (int mi = 0; mi < 4; ++mi)
                af[mi] = *(const bf16x8*)&As[(wm + mi * 16 + l15) * 64 + (((kk * 4 + lq) ^ e7) * 8)];
#pragma unroll
            for (int ni = 0; ni < NI; ++ni)
                bfr[ni] = *(const bf16x8*)&Bs[(wn + ni * 16 + l15) * 64 + (((kk * 4 + lq) ^ e7) * 8)];
#pragma unroll
            for (int mi = 0; mi < 4; ++mi)
#pragma unroll
                for (int ni = 0; ni < NI; ++ni)
                    acc[mi][ni] = __builtin_amdgcn_mfma_f32_16x16x32_bf16(af[mi], bfr[ni], acc[mi][ni], 0, 0, 0);
        }
    }

    if (MODE == 4) {
        float* base;
        int roff;
        if (blockIdx.z == 0) { base = (float*)outp; roff = 0; }
        else if (m0 < rowSplit) { base = pz_lo; roff = 0; }
        else { base = pz_hi; roff = rowSplit; }
#pragma unroll
        for (int mi = 0; mi < 4; ++mi)
#pragma unroll
            for (int ni = 0; ni < NI; ++ni)
#pragma unroll
                for (int r = 0; r < 4; ++r) {
                    const int row = m0 + wm + mi * 16 + lq * 4 + r - roff;
                    const int col = n0 + wn + ni * 16 + l15;
                    base[(size_t)row * N + col] = acc[mi][ni][r];
                }
    } else {
#pragma unroll
        for (int mi = 0; mi < 4; ++mi)
#pragma unroll
            for (int ni = 0; ni < NI; ++ni)
#pragma unroll
                for (int r = 0; r < 4; ++r) {
                    const int row = m0 + wm + mi * 16 + lq * 4 + r;
                    const int col = n0 + wn + ni * 16 + l15;
                    float v = acc[mi][ni][r] + bias[col];
                    if (MODE == 2) v = gelu_f(v);
                    ((UB*)outp)[(size_t)row * N + col] = f2bf(v);
                }
    }
}

// ---------- Flash attention v4 (causal): S^T trick, register-only P ----------
__global__ __launch_bounds__(256)
void flash_attn_kernel(const UB* __restrict__ qkv, UB* __restrict__ outb)
{
    __shared__ UB Ks[64][72];               // 9216 B
    __shared__ unsigned int VtsP[64][36];   // 9216 B, V^T pair-packed, XOR-swizzled

    const int tid = threadIdx.x;
    const int lane = tid & 63;
    const int w = tid >> 6;
    const int l15 = lane & 15;
    const int lq = lane >> 4;
    const int lq8 = lq * 8;

    const int bh = blockIdx.x;              // b*16+h
    const int b = bh >> 4;
    const int h = bh & 15;
    const int by = blockIdx.y;              // 0..31
    const int qt = (by < 16) ? (2 * by + 1) : (62 - 2 * by);   // pairs sum to 31

    const UB* qbase = qkv + (size_t)(b * 2048) * 3072 + h * 64;
    const UB* kbase = qbase + 1024;
    const UB* vbase = qbase + 2048;

    const int q0w = qt * 64 + w * 16;       // wave's first Q row
    const int qrow = q0w + l15;             // lane's q row

    bf16x8 qf[2];
#pragma unroll
    for (int kk = 0; kk < 2; ++kk)
        qf[kk] = *(const bf16x8*)&qbase[(size_t)qrow * 3072 + kk * 32 + lq8];

    floatx4 o[4];                           // O^T: row d = nd*16+lq*4+r, col q = l15
#pragma unroll
    for (int nd = 0; nd < 4; ++nd) o[nd] = (floatx4){0.f, 0.f, 0.f, 0.f};
    float m_r = -1e30f, l_r = 0.f;

    const int krow = tid >> 3;
    const int kch8 = (tid & 7) * 8;
    const int vq = tid >> 3;
    const int vd0 = (tid & 7) * 8;
    const unsigned int vcol = ((((unsigned)vq >> 2) ^ (((unsigned)vd0 >> 3) & 7)) << 2) | (vq & 3);

    const UB* kp0 = kbase + (size_t)krow * 3072 + kch8;
    const UB* kp1 = kp0 + (size_t)32 * 3072;
    const UB* vp0 = vbase + (size_t)(2 * vq) * 3072 + vd0;
    const UB* vp1 = vp0 + 3072;

    uint4 ka = *(const uint4*)kp0;
    uint4 kb = *(const uint4*)kp1;
    uint4 va = *(const uint4*)vp0;
    uint4 vb = *(const uint4*)vp1;

    const float SCL = 0.18033688011112042f;   // 0.125 * log2(e)

    for (int kt = 0; kt <= qt; ++kt) {
        __syncthreads();
        *(uint4*)&Ks[krow][kch8] = ka;
        *(uint4*)&Ks[krow + 32][kch8] = kb;
        {
            const UB* va16 = (const UB*)&va;
            const UB* vb16 = (const UB*)&vb;
#pragma unroll
            for (int j = 0; j < 8; ++j)
                VtsP[vd0 + j][vcol] = (unsigned int)va16[j] | ((unsigned int)vb16[j] << 16);
        }
        __syncthreads();
        if (kt < qt) {
            const size_t off = (size_t)(kt + 1) * 64 * 3072;
            ka = *(const uint4*)(kp0 + off);
            kb = *(const uint4*)(kp1 + off);
            va = *(const uint4*)(vp0 + off);
            vb = *(const uint4*)(vp1 + off);
        }

        const bool needmask = (kt == qt);
        floatx4 sacc[4];                    // S^T: row k = nj*16+lq*4+r, col q = l15
#pragma unroll
        for (int nj = 0; nj < 4; ++nj) {
            bf16x8 ak0 = *(const bf16x8*)&Ks[nj * 16 + l15][lq8];
            bf16x8 ak1 = *(const bf16x8*)&Ks[nj * 16 + l15][32 + lq8];
            floatx4 acc = (floatx4){0.f, 0.f, 0.f, 0.f};
            acc = __builtin_amdgcn_mfma_f32_16x16x32_bf16(ak0, qf[0], acc, 0, 0, 0);
            acc = __builtin_amdgcn_mfma_f32_16x16x32_bf16(ak1, qf[1], acc, 0, 0, 0);
            sacc[nj] = acc;
        }
#pragma unroll
        for (int nj = 0; nj < 4; ++nj)
#pragma unroll
            for (int r = 0; r < 4; ++r) {
                float v = sacc[nj][r] * SCL;
                if (needmask) {
                    const int kcol = kt * 64 + nj * 16 + lq * 4 + r;
                    v = (kcol > qrow) ? -1e30f : v;
                }
                sacc[nj][r] = v;
            }
        {
            float mx = sacc[0][0];
#pragma unroll
            for (int nj = 0; nj < 4; ++nj)
#pragma unroll
                for (int r = 0; r < 4; ++r) mx = fmaxf(mx, sacc[nj][r]);
            mx = fmaxf(mx, __shfl_xor(mx, 16));
            mx = fmaxf(mx, __shfl_xor(mx, 32));
            const float mnew = fmaxf(m_r, mx);
            const float al = __builtin_amdgcn_exp2f(m_r - mnew);
            m_r = mnew;
            float sl = 0.f;
#pragma unroll
            for (int nj = 0; nj < 4; ++nj)
#pragma unroll
                for (int r = 0; r < 4; ++r) {
                    const float p = __builtin_amdgcn_exp2f(sacc[nj][r] - mnew);
                    sacc[nj][r] = p;
                    sl += p;
                }
            sl += __shfl_xor(sl, 16);
            sl += __shfl_xor(sl, 32);
            l_r = l_r * al + sl;
#pragma unroll
            for (int nd = 0; nd < 4; ++nd)
#pragma unroll
                for (int r = 0; r < 4; ++r) o[nd][r] *= al;
        }
#pragma unroll
        for (int nj = 0; nj < 4; ++nj) {
            union { unsigned int u[2]; short4v s; } bp;   // P^T B-frag: k=lq*4+j, n=l15
            bp.u[0] = __builtin_amdgcn_perm(__float_as_uint(sacc[nj][1]),
                                            __float_as_uint(sacc[nj][0]), 0x07060302u);
            bp.u[1] = __builtin_amdgcn_perm(__float_as_uint(sacc[nj][3]),
                                            __float_as_uint(sacc[nj][2]), 0x07060302u);
#pragma unroll
            for (int nd = 0; nd < 4; ++nd) {
                const int d = nd * 16 + l15;
                const int vqb = nj * 2 + (lq >> 1);
                const int col = ((vqb ^ ((d >> 3) & 7)) << 2) | ((lq & 1) * 2);
                short4v aa = *(const short4v*)&VtsP[d][col];   // V^T[d][nj*16+lq*4+j]
                o[nd] = __builtin_amdgcn_mfma_f32_16x16x16bf16_1k(aa, bp.s, o[nd], 0, 0, 0);
            }
        }
    }

    {
        const float inv = 1.0f / l_r;
        UB* orow = outb + (size_t)(b * 2048 + qrow) * 1024 + h * 64;
#pragma unroll
        for (int nd = 0; nd < 4; ++nd) {
            UB o4[4];
#pragma unroll
            for (int r = 0; r < 4; ++r) o4[r] = f2bf(o[nd][r] * inv);
            *(ushort4*)&orow[nd * 16 + lq * 4] = *(ushort4*)o4;
        }
    }
}

// ---------- launch ----------
extern "C" void kernel_launch(void* const* d_in, const int* in_sizes, int n_in,
                              void* d_out, int out_size, void* d_ws, size_t ws_size,
                              hipStream_t stream) {
    const float* x        = (const float*)d_in[0];
    const float* c_attn_w = (const float*)d_in[1];
    const float* c_attn_b = (const float*)d_in[2];
    const float* c_proj_w = (const float*)d_in[3];
    const float* c_proj_b = (const float*)d_in[4];
    const float* mlp_w1   = (const float*)d_in[5];
    const float* mlp_b1   = (const float*)d_in[6];
    const float* mlp_w2   = (const float*)d_in[7];
    const float* mlp_b2   = (const float*)d_in[8];
    const float* ln1_g    = (const float*)d_in[9];
    const float* ln1_b    = (const float*)d_in[10];
    const float* ln2_g    = (const float*)d_in[11];
    const float* ln2_b    = (const float*)d_in[12];
    float* out = (float*)d_out;

    // workspace layout (bytes)
    char* ws = (char*)d_ws;
    UB*    ln_buf  = (UB*)(ws);                          //  8,388,608
    UB*    big_buf = (UB*)(ws + 8388608);                // 33,554,432 (qkv / proj-partial / h1)
    UB*    attout  = (UB*)(ws + 41943040);               //  8,388,608 (attn out / mlp2-partial-lo)
    float* x1      = (float*)(ws + 50331648);            // 16,777,216
    UB*    wt_attn = (UB*)(ws + 67108864);               //  6,291,456
    UB*    wt_proj = (UB*)(ws + 73400320);               //  2,097,152
    UB*    wt_mlp1 = (UB*)(ws + 75497472);               //  8,388,608
    UB*    wt_mlp2 = (UB*)(ws + 83886080);               //  8,388,608

    // 1. transpose weights fp32[K][N] -> bf16[N][K]
    transpose_w_kernel<<<dim3(96, 32), 256, 0, stream>>>(c_attn_w, wt_attn, 1024, 3072);
    transpose_w_kernel<<<dim3(32, 32), 256, 0, stream>>>(c_proj_w, wt_proj, 1024, 1024);
    transpose_w_kernel<<<dim3(128, 32), 256, 0, stream>>>(mlp_w1, wt_mlp1, 1024, 4096);
    transpose_w_kernel<<<dim3(32, 128), 256, 0, stream>>>(mlp_w2, wt_mlp2, 4096, 1024);

    // 2. LN1
    layernorm_kernel<<<4096, 256, 0, stream>>>(x, ln1_g, ln1_b, ln_buf);

    // 3. QKV = LN1 @ Wqkv + b : [4096][3072] bf16 (BN=128: 768 blocks, 3/CU exact)
    gemm_bt_kernel<0, 128><<<dim3(24, 32, 1), 256, 0, stream>>>(ln_buf, wt_attn, c_attn_b,
                                                                big_buf, nullptr, nullptr, 0,
                                                                4096, 3072, 1024, 1024);

    // 4. attention (64-row Q tiles, 1024 blocks)
    flash_attn_kernel<<<dim3(32, 32), 256, 0, stream>>>(big_buf, attout);

    // 5. proj split-K=2 (BN=128, 512 blocks): z0 -> x1, z1 -> big_buf
    gemm_bt_kernel<4, 128><<<dim3(8, 32, 2), 256, 0, stream>>>(attout, wt_proj, nullptr,
                                                               x1, (float*)big_buf, (float*)big_buf, 4096,
                                                               4096, 1024, 1024, 512);
    //    fused: x1 += partial + x + b_proj ; ln_buf = LN2(x1)
    reduce_ln_kernel<<<4096, 256, 0, stream>>>(x1, (float*)big_buf, (float*)big_buf, 4096,
                                               x, c_proj_b, ln2_g, ln2_b, ln_buf);

    // 7. h1 = gelu(LN2 @ W1 + b1) : bf16 [4096][4096] (BN=256: 512 blocks, 2/CU exact)
    gemm_bt_kernel<2, 256><<<dim3(16, 32, 1), 256, 0, stream>>>(ln_buf, wt_mlp1, mlp_b1,
                                                                big_buf, nullptr, nullptr, 0,
                                                                4096, 4096, 1024, 1024);

    // 8. MLP2 split-K=2 (BN=128, 512 blocks): z0 -> out, z1 -> attout/ln_buf
    gemm_bt_kernel<4, 128><<<dim3(8, 32, 2), 256, 0, stream>>>(big_buf, wt_mlp2, nullptr,
                                                               out, (float*)attout, (float*)ln_buf, 2048,
                                                               4096, 1024, 4096, 2048);
    //    out += partial + x1 + b2
    reduce_kernel<<<4096, 256, 0, stream>>>(out, (float*)attout, (float*)ln_buf, 2048,
                                            x1, mlp_b2);
}